// Round 1
// baseline (215.211 us; speedup 1.0000x reference)
//
#include <hip/hip_runtime.h>
#include <math.h>

#define Bb 8
#define Cc 128
#define Nn 3136                  // 56*56 real spatial
#define Np 3200                  // padded spatial (50 x 64)
#define Mm (Bb*Cc*Nn)            // elements per output tensor
#define PADX 136                 // xt row stride (u16): 128 data + 8 pad = 272 B (17x16B)
#define PADV 72                  // s_xc / s_pt row stride (u16): 144 B (9x16B)
#define SHIFT 44.0f              // constant softmax shift (|logit| < 70 << 88)

typedef unsigned short u16;
typedef unsigned int   u32;
typedef __attribute__((ext_vector_type(8)))  u16      u16x8;
typedef __attribute__((ext_vector_type(8)))  _Float16 f16x8;
typedef __attribute__((ext_vector_type(4)))  _Float16 f16x4;
typedef __attribute__((ext_vector_type(4)))  float    f32x4;
typedef __attribute__((ext_vector_type(16))) float    f32x16;

// ---------------------------------------------------------------------------
// Prep: x f32 -> xt [b][n(3200)][PADX] fp16 (spatial-major) + xc [b][c][3200]
// fp16 (channel-major); zero-pads spatial 3136..3199; row_d pads = 1.0.
// Fused: out slot2 = x copy, slot3 = gamma.  grid 400 = 8 b * 50 n-blocks.
// ---------------------------------------------------------------------------
__global__ __launch_bounds__(256) void prep_kernel(const float* __restrict__ x,
                                                   const float* __restrict__ gamma_p,
                                                   float* __restrict__ out,
                                                   u16* __restrict__ xt,
                                                   u16* __restrict__ xc,
                                                   float* __restrict__ row_d) {
    const int bx = blockIdx.x;
    const int b = bx / 50, nblk = bx % 50;
    const int t = threadIdx.x;

    if (nblk == 49) {            // tail: zero-pad spatial rows 3136..3199
        const u16x8 z8 = {0, 0, 0, 0, 0, 0, 0, 0};
        #pragma unroll
        for (int it = 0; it < 4; ++it) {
            const int idx = it * 256 + t, row = idx / 17, seg = idx % 17;
            *(u16x8*)&xt[(size_t)(b * Np + Nn + row) * PADX + seg * 8] = z8;
        }
        if (t < 64) {
            const int idx = 1024 + t, row = idx / 17, seg = idx % 17;
            *(u16x8*)&xt[(size_t)(b * Np + Nn + row) * PADX + seg * 8] = z8;
        }
        #pragma unroll
        for (int it = 0; it < 4; ++it) {
            const int idx = it * 256 + t, c = idx >> 3, seg = idx & 7;
            *(u16x8*)&xc[(size_t)(b * Cc + c) * Np + Nn + seg * 8] = z8;
        }
        if (t < 64) row_d[b * Np + Nn + t] = 1.0f;   // pad denominators: 1/1
        return;
    }

    __shared__ float lx[Cc][65];
    const int n0 = nblk * 64;

    // phase 1: coalesced read + slot-2 copy
    #pragma unroll 8
    for (int r = 0; r < 32; ++r) {
        const int c = r * 4 + (t >> 6);
        const int g = (b * Cc + c) * Nn + n0 + (t & 63);
        const float v = x[g];
        lx[c][t & 63] = v;
        out[(size_t)2 * Mm + g] = v;
    }
    __syncthreads();

    // phase 2: xt rows (n-major, c contiguous)
    {
        const int nl = t & 63, cseg = t >> 6;
        u16x8 hv[4];
        #pragma unroll
        for (int cc = 0; cc < 32; ++cc) {
            const _Float16 hh = (_Float16)lx[cseg * 32 + cc][nl];
            hv[cc >> 3][cc & 7] = __builtin_bit_cast(u16, hh);
        }
        const size_t base = (size_t)(b * Np + n0 + nl) * PADX + cseg * 32;
        #pragma unroll
        for (int k = 0; k < 4; ++k) *(u16x8*)&xt[base + k * 8] = hv[k];
    }
    // phase 2b: xc rows (c-major, n contiguous)
    {
        const int c = t >> 1, half = t & 1;
        u16x8 hv[4];
        #pragma unroll
        for (int k = 0; k < 32; ++k) {
            const _Float16 hh = (_Float16)lx[c][half * 32 + k];
            hv[k >> 3][k & 7] = __builtin_bit_cast(u16, hh);
        }
        const size_t base = (size_t)(b * Cc + c) * Np + n0 + half * 32;
        #pragma unroll
        for (int k = 0; k < 4; ++k) *(u16x8*)&xc[base + k * 8] = hv[k];
    }
    if (bx == 0 && t == 0) out[(size_t)3 * Mm] = gamma_p[0];
}

// ---------------------------------------------------------------------------
// Stats: row_d[b,i] += sum_j exp(e~_ij - 44), 32x32x16 f16 MFMA, dual chains.
// D[m=j][n=i]: A = staged j-rows, B = resident i-rows.
// grid 1568 = 8 b * 49 i-blocks * 4 j-quarters (13/13/12/12 tiles over 50).
// 4-way j-split raises co-residency 3.06 -> ~6 blocks/CU (VGPR=80, LDS=17K).
// ---------------------------------------------------------------------------
__global__ __launch_bounds__(256, 3) void stats_kernel(const u16* __restrict__ xt,
                                                       float* __restrict__ row_d) {
    __shared__ u16 s_jt[64 * PADX];   // 17408 B

    const int bx = blockIdx.x;
    const int b = bx / 196, rem = bx % 196;
    const int i0 = (rem >> 2) * 64, jq = rem & 3;
    const int t = threadIdx.x;
    const int w = t >> 6, l = t & 63, lane = l & 31, h = l >> 5;
    const int igrp = w & 1, jsub = w >> 1;

    f16x8 Bf[8];
    {
        const size_t rb = (size_t)(b * Np + i0 + igrp * 32 + lane) * PADX + h * 8;
        #pragma unroll
        for (int kk = 0; kk < 8; ++kk)
            Bf[kk] = *(const f16x8*)&xt[rb + kk * 16];
    }

    float sa = 0.0f, sb = 0.0f;
    const int jt0 = jq * 12 + (jq < 2 ? jq : 2);     // 0, 13, 26, 38
    const int jcnt = 12 + (jq < 2 ? 1 : 0);          // 13, 13, 12, 12

    for (int jt = jt0; jt < jt0 + jcnt; ++jt) {
        const int j0 = jt * 64;
        __syncthreads();
        {   // contiguous copy: 64 rows x 17 segs
            const u16* src = xt + (size_t)(b * Np + j0) * PADX;
            u16x8 tv[4], tv4;
            #pragma unroll
            for (int it = 0; it < 4; ++it)
                tv[it] = *(const u16x8*)&src[(it * 256 + t) * 8];
            if (t < 64) tv4 = *(const u16x8*)&src[(1024 + t) * 8];
            #pragma unroll
            for (int it = 0; it < 4; ++it)
                *(u16x8*)&s_jt[(it * 256 + t) * 8] = tv[it];
            if (t < 64) *(u16x8*)&s_jt[(1024 + t) * 8] = tv4;
        }
        __syncthreads();

        f32x16 ea, eb;
        #pragma unroll
        for (int r = 0; r < 16; ++r) { ea[r] = 0.0f; eb[r] = 0.0f; }
        const int arow = (jsub * 32 + lane) * PADX + h * 8;
        #pragma unroll
        for (int kk = 0; kk < 4; ++kk) {
            const f16x8 A0 = *(const f16x8*)&s_jt[arow + (2 * kk) * 16];
            const f16x8 A1 = *(const f16x8*)&s_jt[arow + (2 * kk + 1) * 16];
            ea = __builtin_amdgcn_mfma_f32_32x32x16_f16(A0, Bf[2 * kk], ea, 0, 0, 0);
            eb = __builtin_amdgcn_mfma_f32_32x32x16_f16(A1, Bf[2 * kk + 1], eb, 0, 0, 0);
        }

        const bool diag = (j0 == i0) && (jsub == igrp);
        #pragma unroll
        for (int r = 0; r < 16; ++r) {
            const int mrow = (r & 3) + 8 * (r >> 2) + 4 * h;
            float v = ea[r] + eb[r];
            if (diag && (mrow == lane)) v = 0.0f;
            if (r & 1) sb += __expf(v - SHIFT); else sa += __expf(v - SHIFT);
        }
    }

    float ssum = sa + sb;
    ssum += __shfl_xor(ssum, 32, 64);   // combine h-halves (disjoint j-rows)
    if (h == 0) atomicAdd(&row_d[b * Np + i0 + igrp * 32 + lane], ssum);
}

// ---------------------------------------------------------------------------
// Out: partial_ih[c][j] = sum_{i in half ih} V[c][i]*exp(e~_ij-44)/d_i.
// grid 784 = (b, 64-j, ih): i-range split in two halves of 25 tiles each ->
// 3 blocks/CU co-resident (LDS limit) instead of 1.53 grid-bound.
// Raw f32 partials go to out slot-ih as scratch; finish_kernel combines.
// Energy: wave (isub, jgrp): D[m=i32][n=j32], B = resident j-frags;
//   P -> s_pt[j][i] (b64 writes). PV: wave (cp, jg): D[m=c][n=j], two
//   c-tiles (cp*64, cp*64+32), K=64, single accumulator pair, no reduction.
// ---------------------------------------------------------------------------
__global__ __launch_bounds__(256, 3) void out_kernel(const u16* __restrict__ xt,
                                                     const u16* __restrict__ xc,
                                                     const float* __restrict__ row_d,
                                                     float* __restrict__ out) {
    __shared__ u16 s_xt[64 * PADX];    // 17408 B  i-tile, [i][c]
    __shared__ u16 s_xc[Cc * PADV];    // 18432 B  V tile, [c][i]
    __shared__ u16 s_pt[64 * PADV];    //  9216 B  P^T,    [j][i]

    const int bx = blockIdx.x;
    const int b = bx / 98, rem = bx % 98;
    const int j0 = (rem >> 1) * 64, ih = rem & 1;
    const int t = threadIdx.x;
    const int w = t >> 6, l = t & 63, lane = l & 31, h = l >> 5;
    const int isub = w & 1, jgrp = w >> 1;   // energy roles
    const int jg = w & 1,  cp = w >> 1;      // PV roles
    const u16* __restrict__ xtb = xt + (size_t)b * Np * PADX;
    const u16* __restrict__ xcb = xc + (size_t)b * Cc * Np;

    // resident B-frags: j-rows j0 + jgrp*32 + lane
    f16x8 Bj[8];
    {
        const size_t rb = (size_t)(j0 + jgrp * 32 + lane) * PADX + h * 8;
        #pragma unroll
        for (int kk = 0; kk < 8; ++kk)
            Bj[kk] = *(const f16x8*)&xtb[rb + kk * 16];
    }

    f32x16 oa, ob;
    #pragma unroll
    for (int r = 0; r < 16; ++r) { oa[r] = 0.0f; ob[r] = 0.0f; }

    for (int ti = ih * 25; ti < ih * 25 + 25; ++ti) {
        const int i0g = ti * 64;
        __syncthreads();                     // prior-iter s_xt/s_xc/s_pt reads done
        // stage: s_xt = contiguous 1088 segs; s_xc = 128 c-rows x 8 segs
        {
            const u16* srct = xtb + (size_t)i0g * PADX;
            u16x8 vt[4], vt4, vcr[4];
            #pragma unroll
            for (int it = 0; it < 4; ++it) {
                vt[it] = *(const u16x8*)&srct[(it * 256 + t) * 8];
                const int q = it * 256 + t;
                vcr[it] = *(const u16x8*)&xcb[(size_t)(q >> 3) * Np + i0g + (q & 7) * 8];
            }
            if (t < 64) vt4 = *(const u16x8*)&srct[(1024 + t) * 8];
            #pragma unroll
            for (int it = 0; it < 4; ++it) {
                *(u16x8*)&s_xt[(it * 256 + t) * 8] = vt[it];
                const int q = it * 256 + t;
                *(u16x8*)&s_xc[(q >> 3) * PADV + (q & 7) * 8] = vcr[it];
            }
            if (t < 64) *(u16x8*)&s_xt[(1024 + t) * 8] = vt4;
        }
        __syncthreads();                     // tiles staged

        // energy: D[m=i][n=j], one 32x32 tile per wave, dual K-chains
        f32x16 ea, eb;
        #pragma unroll
        for (int r = 0; r < 16; ++r) { ea[r] = 0.0f; eb[r] = 0.0f; }
        const int arow = (isub * 32 + lane) * PADX + h * 8;
        #pragma unroll
        for (int kk = 0; kk < 4; ++kk) {
            const f16x8 A0 = *(const f16x8*)&s_xt[arow + (2 * kk) * 16];
            const f16x8 A1 = *(const f16x8*)&s_xt[arow + (2 * kk + 1) * 16];
            ea = __builtin_amdgcn_mfma_f32_32x32x16_f16(A0, Bj[2 * kk], ea, 0, 0, 0);
            eb = __builtin_amdgcn_mfma_f32_32x32x16_f16(A1, Bj[2 * kk + 1], eb, 0, 0, 0);
        }

        // P = exp(masked e - 44)/d -> s_pt[j][i], 4x b64 per wave
        const bool mayDiag = (j0 < i0g + 64) && (i0g < j0 + 64);
        const int ptbase = (jgrp * 32 + lane) * PADV + isub * 32;
        #pragma unroll
        for (int q = 0; q < 4; ++q) {
            const f32x4 dq = *(const f32x4*)&row_d[b * Np + i0g + isub * 32 + q * 8 + h * 4];
            f16x4 pv;
            #pragma unroll
            for (int r = 0; r < 4; ++r) {
                const int m = q * 8 + h * 4 + r;
                float v = ea[q * 4 + r] + eb[q * 4 + r];
                if (mayDiag && (i0g + isub * 32 + m == j0 + jgrp * 32 + lane)) v = 0.0f;
                pv[r] = (_Float16)(__expf(v - SHIFT) * __builtin_amdgcn_rcpf(dq[r]));
            }
            *(f16x4*)&s_pt[ptbase + q * 8 + h * 4] = pv;
        }
        __syncthreads();                     // s_pt complete (cross-wave reads next)

        // PV: D[m=c][n=j], K=64; wave (cp, jg): c-tiles cp*64 and cp*64+32
        const int pbrow = (jg * 32 + lane) * PADV + h * 8;
        const int va0 = (cp * 64 + lane) * PADV + h * 8;
        const int va1 = va0 + 32 * PADV;
        #pragma unroll
        for (int kk = 0; kk < 4; ++kk) {
            const f16x8 Bp  = *(const f16x8*)&s_pt[pbrow + kk * 16];
            const f16x8 Av0 = *(const f16x8*)&s_xc[va0 + kk * 16];
            const f16x8 Av1 = *(const f16x8*)&s_xc[va1 + kk * 16];
            oa = __builtin_amdgcn_mfma_f32_32x32x16_f16(Av0, Bp, oa, 0, 0, 0);
            ob = __builtin_amdgcn_mfma_f32_32x32x16_f16(Av1, Bp, ob, 0, 0, 0);
        }
    }

    // epilogue: raw f32 partials -> out slot ih (scratch until finish_kernel)
    #pragma unroll
    for (int r = 0; r < 16; ++r) {
        const int mrow = (r & 3) + 8 * (r >> 2) + 4 * h;
        const int jj = j0 + jg * 32 + lane;
        {
            const int c = cp * 64 + mrow;
            const size_t pos = (size_t)(b * Cc + c) * Nn + jj;
            out[(size_t)ih * Mm + pos] = oa[r];
        }
        {
            const int c = cp * 64 + 32 + mrow;
            const size_t pos = (size_t)(b * Cc + c) * Nn + jj;
            out[(size_t)ih * Mm + pos] = ob[r];
        }
    }
}

// ---------------------------------------------------------------------------
// Finish: o = relu(p0 + p1); slot0 = gamma*o + x; slot1 = o.
// Pure streaming: 38.5 MB read + 25.7 MB write. grid 3136 x 256 x f32x4.
// ---------------------------------------------------------------------------
__global__ __launch_bounds__(256) void finish_kernel(const float* __restrict__ x,
                                                     const float* __restrict__ gamma_p,
                                                     float* __restrict__ out) {
    const float gamma = gamma_p[0];
    const size_t base = ((size_t)blockIdx.x * 256 + threadIdx.x) * 4;
    const f32x4 pa = *(const f32x4*)&out[base];
    const f32x4 pb = *(const f32x4*)&out[(size_t)Mm + base];
    const f32x4 xv = *(const f32x4*)&x[base];
    f32x4 yo, oo;
    #pragma unroll
    for (int r = 0; r < 4; ++r) {
        const float o = fmaxf(pa[r] + pb[r], 0.0f);
        oo[r] = o;
        yo[r] = fmaf(gamma, o, xv[r]);
    }
    *(f32x4*)&out[base] = yo;
    *(f32x4*)&out[(size_t)Mm + base] = oo;
}

extern "C" void kernel_launch(void* const* d_in, const int* in_sizes, int n_in,
                              void* d_out, int out_size, void* d_ws, size_t ws_size,
                              hipStream_t stream) {
    const float* x       = (const float*)d_in[0];
    const float* gamma_p = (const float*)d_in[1];
    float* out = (float*)d_out;

    // ws layout (~13.7 MB): row_d (8x3200 f32) | xt | xc
    float* row_d = (float*)d_ws;
    u16* xt = (u16*)((char*)d_ws + (1 << 17));
    u16* xc = xt + (size_t)Bb * Np * PADX;

    hipMemsetAsync(row_d, 0, (size_t)Bb * Np * sizeof(float), stream);
    prep_kernel  <<<400, 256, 0, stream>>>(x, gamma_p, out, xt, xc, row_d);
    stats_kernel <<<1568, 256, 0, stream>>>(xt, row_d);
    out_kernel   <<<784, 256, 0, stream>>>(xt, xc, row_d, out);
    finish_kernel<<<3136, 256, 0, stream>>>(x, gamma_p, out);
}

// Round 2
// 190.892 us; speedup vs baseline: 1.1274x; 1.1274x over previous
//
#include <hip/hip_runtime.h>
#include <math.h>

#define Bb 8
#define Cc 128
#define Nn 3136                  // 56*56 real spatial
#define Np 3200                  // padded spatial (50 x 64)
#define NT 50                    // 64-row tiles per batch
#define Mm (Bb*Cc*Nn)            // elements per output tensor
#define PADV 72                  // s_pt row stride (u16): 144 B (9x16B)
#define L2E 1.44269504088896340736f
#define C44 (44.0f * L2E)        // shift 44 in log2 domain

// xt2: [b][T(50)][seg(16)][row(64)][8 u16]   seg = channel-chunk of 8
#define XT2B (NT*16*64*8)        // 409600 u16 per batch
// xc2: [b][T(50)][seg(8)][c(128)][8 u16]     seg = i-chunk of 8
#define XC2B (NT*8*128*8)        // 409600 u16 per batch

typedef unsigned short u16;
typedef __attribute__((ext_vector_type(8)))  u16      u16x8;
typedef __attribute__((ext_vector_type(8)))  _Float16 f16x8;
typedef __attribute__((ext_vector_type(4)))  _Float16 f16x4;
typedef __attribute__((ext_vector_type(4)))  float    f32x4;
typedef __attribute__((ext_vector_type(16))) float    f32x16;

__device__ __forceinline__ float exp2fast(float x) {
#if __has_builtin(__builtin_amdgcn_exp2f)
    return __builtin_amdgcn_exp2f(x);
#else
    float r; asm volatile("v_exp_f32 %0, %1" : "=v"(r) : "v"(x)); return r;
#endif
}

// ---------------------------------------------------------------------------
// Prep: x f32 -> fragment-major fp16 tiles xt2/xc2 (all later MFMA fragment
// loads become perfectly coalesced global loads). Fused: out slot2 = x copy,
// slot3 = gamma. grid 400 = 8 b * 50 n-blocks; nblk 49 zero-pads tile 49.
// ---------------------------------------------------------------------------
__global__ __launch_bounds__(256) void prep_kernel(const float* __restrict__ x,
                                                   const float* __restrict__ gamma_p,
                                                   float* __restrict__ out,
                                                   u16* __restrict__ xt2,
                                                   u16* __restrict__ xc2,
                                                   float* __restrict__ row_d) {
    const int bx = blockIdx.x;
    const int b = bx / 50, nblk = bx % 50;
    const int t = threadIdx.x;

    if (nblk == 49) {            // pad tile: rows 3136..3199 all zero
        const u16x8 z8 = {0, 0, 0, 0, 0, 0, 0, 0};
        u16* dt = xt2 + ((size_t)b * NT + 49) * (16 * 64 * 8);
        u16* dc = xc2 + ((size_t)b * NT + 49) * (8 * 128 * 8);
        #pragma unroll
        for (int it = 0; it < 4; ++it) {
            *(u16x8*)&dt[(it * 256 + t) * 8] = z8;
            *(u16x8*)&dc[(it * 256 + t) * 8] = z8;
        }
        if (t < 64) row_d[b * Np + Nn + t] = 1.0f;   // pad denominators: 1
        return;
    }

    __shared__ float lx[Cc][65];
    const int n0 = nblk * 64;

    // phase 1: coalesced read + slot-2 copy
    #pragma unroll 8
    for (int r = 0; r < 32; ++r) {
        const int c = r * 4 + (t >> 6);
        const int g = (b * Cc + c) * Nn + n0 + (t & 63);
        const float v = x[g];
        lx[c][t & 63] = v;
        out[(size_t)2 * Mm + g] = v;
    }
    __syncthreads();

    // phase 2: xt2 — thread (row nl, cseg) -> segs cseg*4+k, fully coalesced
    {
        const int nl = t & 63, cseg = t >> 6;
        u16x8 hv[4];
        #pragma unroll
        for (int cc = 0; cc < 32; ++cc) {
            const _Float16 hh = (_Float16)lx[cseg * 32 + cc][nl];
            hv[cc >> 3][cc & 7] = __builtin_bit_cast(u16, hh);
        }
        u16* base = xt2 + (((size_t)(b * NT + nblk) * 16 + cseg * 4) * 64 + nl) * 8;
        #pragma unroll
        for (int k = 0; k < 4; ++k) *(u16x8*)&base[k * (64 * 8)] = hv[k];
    }
    // phase 2b: xc2 — thread (c, half) -> segs half*4+k
    {
        const int c = t >> 1, half = t & 1;
        u16x8 hv[4];
        #pragma unroll
        for (int k = 0; k < 32; ++k) {
            const _Float16 hh = (_Float16)lx[c][half * 32 + k];
            hv[k >> 3][k & 7] = __builtin_bit_cast(u16, hh);
        }
        u16* base = xc2 + (((size_t)(b * NT + nblk) * 8 + half * 4) * 128 + c) * 8;
        #pragma unroll
        for (int k = 0; k < 4; ++k) *(u16x8*)&base[k * (128 * 8)] = hv[k];
    }
    if (bx == 0 && t == 0) out[(size_t)3 * Mm] = gamma_p[0];
}

// ---------------------------------------------------------------------------
// Stats: row_d[b,i] += sum_j exp(e_ij - 44). NO LDS, NO barriers: fragment
// loads direct from L2-resident xt2 (coalesced). Single MFMA chain.
// grid 1568 = 49 i-blocks * 4 j-quarters * 8 b (b = bx&7 -> XCD-pinned L2).
// ---------------------------------------------------------------------------
__global__ __launch_bounds__(256, 5) void stats_kernel(const u16* __restrict__ xt2,
                                                       float* __restrict__ row_d) {
    const int bx = blockIdx.x;
    const int b = bx & 7, rem = bx >> 3;
    const int i0t = rem >> 2, jq = rem & 3;      // i-tile 0..48
    const int t = threadIdx.x;
    const int w = t >> 6, l = t & 63, lane = l & 31, h = l >> 5;
    const int igrp = w & 1, jsub = w >> 1;
    const u16* __restrict__ xb = xt2 + (size_t)b * XT2B;

    f16x8 Bf[8];                                 // resident i-row fragments
    const int irow = igrp * 32 + lane;
    #pragma unroll
    for (int kk = 0; kk < 8; ++kk)
        Bf[kk] = *(const f16x8*)&xb[(((size_t)i0t * 16 + 2 * kk + h) * 64 + irow) * 8];

    float sa = 0.f, sb = 0.f;
    const int jt0 = jq * 12 + (jq < 2 ? jq : 2); // 0, 13, 26, 38
    const int jcnt = 12 + (jq < 2 ? 1 : 0);      // 13, 13, 12, 12
    const int jrow = jsub * 32 + lane;

    for (int jt = jt0; jt < jt0 + jcnt; ++jt) {
        const u16* ab = &xb[((size_t)jt * 16 * 64 + jrow) * 8];
        f32x16 acc;
        #pragma unroll
        for (int r = 0; r < 16; ++r) acc[r] = 0.f;
        #pragma unroll
        for (int kk = 0; kk < 8; ++kk) {
            const f16x8 A = *(const f16x8*)&ab[(2 * kk + h) * 512];
            acc = __builtin_amdgcn_mfma_f32_32x32x16_f16(A, Bf[kk], acc, 0, 0, 0);
        }
        if (jt == i0t) {                          // diagonal tile: masked path
            const bool dsub = (jsub == igrp);
            #pragma unroll
            for (int r = 0; r < 16; ++r) {
                const int mrow = (r & 3) + 8 * (r >> 2) + 4 * h;
                float v = acc[r];
                if (dsub && mrow == lane) v = 0.f;
                const float e = exp2fast(fmaf(v, L2E, -C44));
                if (r & 1) sb += e; else sa += e;
            }
        } else {                                  // clean path: fma+exp+add
            #pragma unroll
            for (int r = 0; r < 16; ++r) {
                const float e = exp2fast(fmaf(acc[r], L2E, -C44));
                if (r & 1) sb += e; else sa += e;
            }
        }
    }
    float ssum = sa + sb;
    ssum += __shfl_xor(ssum, 32, 64);   // combine h-halves (disjoint j-rows)
    if (h == 0) atomicAdd(&row_d[b * Np + i0t * 64 + igrp * 32 + lane], ssum);
}

// ---------------------------------------------------------------------------
// Conv: row_d -> c_i = 44*log2e + log2(d_i), so P = exp2(e*log2e - c_i)
// (folds the softmax divide into the exponent). 25600 elems, in-place.
// ---------------------------------------------------------------------------
__global__ __launch_bounds__(256) void conv_kernel(float* __restrict__ row_d) {
    const int i = blockIdx.x * 256 + threadIdx.x;
    row_d[i] = C44 + __log2f(row_d[i]);
}

// ---------------------------------------------------------------------------
// Out: partial_ih[c][j] = sum_{i half} V[c][i] * exp2(e*l2e - c_i).
// LDS = only P^T double-buffer (18432 B) -> 1 barrier/iter; all A/B/V
// fragments load coalesced from L2 (xt2/xc2). grid 784 = 49 j * 2 ih * 8 b.
// Raw f32 partials -> out slot ih; finish_kernel combines.
// ---------------------------------------------------------------------------
__global__ __launch_bounds__(256, 3) void out_kernel(const u16* __restrict__ xt2,
                                                     const u16* __restrict__ xc2,
                                                     const float* __restrict__ row_c,
                                                     float* __restrict__ out) {
    __shared__ u16 s_pt[2][64 * PADV];           // P^T dbuf, 2 x 9216 B

    const int bx = blockIdx.x;
    const int b = bx & 7, rem = bx >> 3;
    const int j0t = rem >> 1, ih = rem & 1;      // j-tile 0..48, i-half
    const int t = threadIdx.x;
    const int w = t >> 6, l = t & 63, lane = l & 31, h = l >> 5;
    const int isub = w & 1, jgrp = w >> 1;       // energy roles
    const int jg = w & 1,  cp = w >> 1;          // PV roles
    const u16* __restrict__ xtb = xt2 + (size_t)b * XT2B;
    const u16* __restrict__ xcb = xc2 + (size_t)b * XC2B;

    f16x8 Bj[8];                                 // resident j-row fragments
    const int jrow = jgrp * 32 + lane;
    #pragma unroll
    for (int kk = 0; kk < 8; ++kk)
        Bj[kk] = *(const f16x8*)&xtb[(((size_t)j0t * 16 + 2 * kk + h) * 64 + jrow) * 8];

    f32x16 oa, ob;
    #pragma unroll
    for (int r = 0; r < 16; ++r) { oa[r] = 0.f; ob[r] = 0.f; }

    const int arow = isub * 32 + lane;
    const int ptbase = (jgrp * 32 + lane) * PADV + isub * 32;
    const int pbrow = (jg * 32 + lane) * PADV + h * 8;

    for (int ti = ih * 25; ti < ih * 25 + 25; ++ti) {
        // energy: single-chain MFMA, A-frags direct from global
        f32x16 ea;
        #pragma unroll
        for (int r = 0; r < 16; ++r) ea[r] = 0.f;
        const u16* ab = &xtb[((size_t)ti * 16 * 64 + arow) * 8];
        #pragma unroll
        for (int kk = 0; kk < 8; ++kk) {
            const f16x8 A = *(const f16x8*)&ab[(2 * kk + h) * 512];
            ea = __builtin_amdgcn_mfma_f32_32x32x16_f16(A, Bj[kk], ea, 0, 0, 0);
        }

        // P = exp2(e*l2e - c_i) -> s_pt[ti&1]; diag branch hoisted
        u16* pt = &s_pt[ti & 1][0];
        const float* cbase = &row_c[b * Np + ti * 64 + isub * 32];
        if (ti == j0t) {
            const bool dsub = (isub == jgrp);
            #pragma unroll
            for (int q = 0; q < 4; ++q) {
                const f32x4 cv = *(const f32x4*)&cbase[q * 8 + h * 4];
                f16x4 pv;
                #pragma unroll
                for (int r = 0; r < 4; ++r) {
                    const int m = q * 8 + h * 4 + r;
                    float v = ea[q * 4 + r];
                    if (dsub && m == lane) v = 0.f;
                    pv[r] = (_Float16)exp2fast(fmaf(v, L2E, -cv[r]));
                }
                *(f16x4*)&pt[ptbase + q * 8 + h * 4] = pv;
            }
        } else {
            #pragma unroll
            for (int q = 0; q < 4; ++q) {
                const f32x4 cv = *(const f32x4*)&cbase[q * 8 + h * 4];
                f16x4 pv;
                #pragma unroll
                for (int r = 0; r < 4; ++r)
                    pv[r] = (_Float16)exp2fast(fmaf(ea[q * 4 + r], L2E, -cv[r]));
                *(f16x4*)&pt[ptbase + q * 8 + h * 4] = pv;
            }
        }
        __syncthreads();                         // s_pt[ti&1] complete

        // PV: V-frags direct from global; Bp from s_pt
        const u16* vb = &xcb[((size_t)ti * 8 * 128 + cp * 64 + lane) * 8];
        #pragma unroll
        for (int kk = 0; kk < 4; ++kk) {
            const f16x8 Bp  = *(const f16x8*)&pt[pbrow + kk * 16];
            const f16x8 Av0 = *(const f16x8*)&vb[((2 * kk + h) * 128) * 8];
            const f16x8 Av1 = *(const f16x8*)&vb[((2 * kk + h) * 128 + 32) * 8];
            oa = __builtin_amdgcn_mfma_f32_32x32x16_f16(Av0, Bp, oa, 0, 0, 0);
            ob = __builtin_amdgcn_mfma_f32_32x32x16_f16(Av1, Bp, ob, 0, 0, 0);
        }
    }

    // epilogue: raw f32 partials -> out slot ih (scratch until finish_kernel)
    #pragma unroll
    for (int r = 0; r < 16; ++r) {
        const int mrow = (r & 3) + 8 * (r >> 2) + 4 * h;
        const int jj = j0t * 64 + jg * 32 + lane;
        {
            const int c = cp * 64 + mrow;
            const size_t pos = (size_t)(b * Cc + c) * Nn + jj;
            out[(size_t)ih * Mm + pos] = oa[r];
        }
        {
            const int c = cp * 64 + 32 + mrow;
            const size_t pos = (size_t)(b * Cc + c) * Nn + jj;
            out[(size_t)ih * Mm + pos] = ob[r];
        }
    }
}

// ---------------------------------------------------------------------------
// Finish: o = relu(p0 + p1); slot0 = gamma*o + x; slot1 = o. Pure streaming.
// ---------------------------------------------------------------------------
__global__ __launch_bounds__(256) void finish_kernel(const float* __restrict__ x,
                                                     const float* __restrict__ gamma_p,
                                                     float* __restrict__ out) {
    const float gamma = gamma_p[0];
    const size_t base = ((size_t)blockIdx.x * 256 + threadIdx.x) * 4;
    const f32x4 pa = *(const f32x4*)&out[base];
    const f32x4 pb = *(const f32x4*)&out[(size_t)Mm + base];
    const f32x4 xv = *(const f32x4*)&x[base];
    f32x4 yo, oo;
    #pragma unroll
    for (int r = 0; r < 4; ++r) {
        const float o = fmaxf(pa[r] + pb[r], 0.0f);
        oo[r] = o;
        yo[r] = fmaf(gamma, o, xv[r]);
    }
    *(f32x4*)&out[base] = yo;
    *(f32x4*)&out[(size_t)Mm + base] = oo;
}

extern "C" void kernel_launch(void* const* d_in, const int* in_sizes, int n_in,
                              void* d_out, int out_size, void* d_ws, size_t ws_size,
                              hipStream_t stream) {
    const float* x       = (const float*)d_in[0];
    const float* gamma_p = (const float*)d_in[1];
    float* out = (float*)d_out;

    // ws layout (~12.6 MB): row_d (8x3200 f32, 128K reserved) | xt2 | xc2
    float* row_d = (float*)d_ws;
    u16* xt2 = (u16*)((char*)d_ws + (1 << 17));
    u16* xc2 = xt2 + (size_t)Bb * XT2B;

    hipMemsetAsync(row_d, 0, (size_t)Bb * Np * sizeof(float), stream);
    prep_kernel  <<<400, 256, 0, stream>>>(x, gamma_p, out, xt2, xc2, row_d);
    stats_kernel <<<1568, 256, 0, stream>>>(xt2, row_d);
    conv_kernel  <<<100, 256, 0, stream>>>(row_d);
    out_kernel   <<<784, 256, 0, stream>>>(xt2, xc2, row_d, out);
    finish_kernel<<<3136, 256, 0, stream>>>(x, gamma_p, out);
}